// Round 4
// baseline (641.271 us; speedup 1.0000x reference)
//
#include <hip/hip_runtime.h>
#include <math.h>

// SeesawLoss forward: B=8192 rows, C=4096 classes, P=0.8, Q=2.0, EPS=0.01
// nll_b = M2 + log(sum_j exp(logit_bj - M2)) - o_{b,t}
// logit_bj = o_bj + P*(la_j - la_t)[la_j < la_t] + Q*(ls_j - logclip)[> 0]
// where ls_j = o_j - M - lse1 (log-softmax of detached outputs),
//       logclip = max(ls_t, log(EPS)).
// Row is register-resident (16 floats/thread x 256 threads); no LDS staging.
// Final mean via fixed-point int64 atomic (order-independent -> deterministic).

#define CC 4096
#define SCALE_D 16777216.0   // 2^24 fixed-point scale for the nll sum

__device__ __forceinline__ float wave_max(float v) {
    #pragma unroll
    for (int o = 32; o > 0; o >>= 1) v = fmaxf(v, __shfl_xor(v, o, 64));
    return v;
}
__device__ __forceinline__ float wave_sum(float v) {
    #pragma unroll
    for (int o = 32; o > 0; o >>= 1) v += __shfl_xor(v, o, 64);
    return v;
}

// One block: bincount via LDS atomics -> clamp -> log table.
// Also zeroes the fixed-point accumulator + completion counter for this call.
__global__ __launch_bounds__(1024) void k_hist(const int* __restrict__ tg, int B,
                                               float* __restrict__ logacc,
                                               unsigned long long* __restrict__ fsum,
                                               unsigned int* __restrict__ counter) {
    __shared__ int hacc[CC];
    const int tid = threadIdx.x;
    #pragma unroll
    for (int k = 0; k < CC / 1024; ++k) hacc[tid + k * 1024] = 0;
    __syncthreads();
    for (int i = tid; i < B; i += 1024) atomicAdd(&hacc[tg[i]], 1);
    __syncthreads();
    #pragma unroll
    for (int k = 0; k < CC / 1024; ++k) {
        int i = tid + k * 1024;
        int a = hacc[i];
        if (a < 1) a = 1;                 // clamp(min=1)
        logacc[i] = __logf((float)a);
    }
    if (tid == 0) { *fsum = 0ULL; *counter = 0u; }
}

__global__ __launch_bounds__(256, 8) void k_row(const float* __restrict__ outp,
                                                const int* __restrict__ tg,
                                                const float* __restrict__ logacc,
                                                unsigned long long* __restrict__ fsum,
                                                unsigned int* __restrict__ counter,
                                                float* __restrict__ out, int B) {
    __shared__ float red_m[4], red_s[4], red_m2[4], red_s2[4];

    const int b   = blockIdx.x;
    const int tid = threadIdx.x;
    const int w   = tid >> 6;
    const bool lane0 = (tid & 63) == 0;

    constexpr float P_ = 0.8f, Q_ = 2.0f;
    const float LOG_EPS = -4.605170185988091f;   // log(0.01)

    const float4* __restrict__ src = (const float4*)(outp + (size_t)b * CC);
    const float4* __restrict__ lac = (const float4*)logacc;

    // ---- load row into registers (16 floats/thread), partial max ----
    float4 v[4];
    float m = -1e30f;
    #pragma unroll
    for (int k = 0; k < 4; ++k) {
        v[k] = src[tid + k * 256];
        m = fmaxf(m, fmaxf(fmaxf(v[k].x, v[k].y), fmaxf(v[k].z, v[k].w)));
    }

    const int   t    = tg[b];
    const float o_t  = outp[(size_t)b * CC + t];   // L2-hot (just streamed)
    const float la_t = logacc[t];

    m = wave_max(m);
    if (lane0) red_m[w] = m;
    __syncthreads();
    const float M = fmaxf(fmaxf(red_m[0], red_m[1]), fmaxf(red_m[2], red_m[3]));

    // ---- sum exp(o - M) from registers ----
    float s = 0.f;
    #pragma unroll
    for (int k = 0; k < 4; ++k) {
        s += __expf(v[k].x - M);
        s += __expf(v[k].y - M);
        s += __expf(v[k].z - M);
        s += __expf(v[k].w - M);
    }
    s = wave_sum(s);
    if (lane0) red_s[w] = s;
    __syncthreads();
    const float S    = (red_s[0] + red_s[1]) + (red_s[2] + red_s[3]);
    const float lse1 = __logf(S);

    const float ls_t    = o_t - M - lse1;
    const float logclip = fmaxf(ls_t, LOG_EPS);
    const float Koff    = M + lse1 + logclip;      // d_j = o_j - Koff

    // ---- logits in place, partial max ----
    // at j==t both predicates are exactly false -> extra == 0 (== (1-onehot) mask)
    float m2 = -1e30f;
    #pragma unroll
    for (int k = 0; k < 4; ++k) {
        float4 la = lac[tid + k * 256];
        float* pv = (float*)&v[k];
        float* pl = (float*)&la;
        #pragma unroll
        for (int c = 0; c < 4; ++c) {
            float o  = pv[c];
            float mit = (pl[c] < la_t) ? P_ * (pl[c] - la_t) : 0.f;  // <= 0
            float d   = o - Koff;
            float cmp = (d > 0.f) ? Q_ * d : 0.f;                    // >= 0
            float lg  = o + mit + cmp;
            pv[c] = lg;
            m2 = fmaxf(m2, lg);
        }
    }
    m2 = wave_max(m2);
    if (lane0) red_m2[w] = m2;
    __syncthreads();
    const float M2 = fmaxf(fmaxf(red_m2[0], red_m2[1]), fmaxf(red_m2[2], red_m2[3]));

    // ---- sum exp(logit - M2) ----
    float s2 = 0.f;
    #pragma unroll
    for (int k = 0; k < 4; ++k) {
        s2 += __expf(v[k].x - M2);
        s2 += __expf(v[k].y - M2);
        s2 += __expf(v[k].z - M2);
        s2 += __expf(v[k].w - M2);
    }
    s2 = wave_sum(s2);
    if (lane0) red_s2[w] = s2;
    __syncthreads();

    if (tid == 0) {
        float S2   = (red_s2[0] + red_s2[1]) + (red_s2[2] + red_s2[3]);
        float nllv = M2 + __logf(S2) - o_t;        // >= 0
        long long q = (long long)((double)nllv * SCALE_D + 0.5);
        atomicAdd(fsum, (unsigned long long)q);
        __threadfence();
        unsigned int done = atomicAdd(counter, 1u);
        if (done == (unsigned int)(gridDim.x - 1)) {
            unsigned long long total = atomicAdd(fsum, 0ULL);  // device-scope read
            out[0] = (float)((double)(long long)total / SCALE_D / (double)B);
        }
    }
}

extern "C" void kernel_launch(void* const* d_in, const int* in_sizes, int n_in,
                              void* d_out, int out_size, void* d_ws, size_t ws_size,
                              hipStream_t stream) {
    const float* outp = (const float*)d_in[0];   // [B, C] f32
    const int*   tg   = (const int*)d_in[1];     // [B] i32
    float*       out  = (float*)d_out;           // scalar f32

    const int B = in_sizes[1];                   // 8192 (C fixed at 4096)

    char* ws = (char*)d_ws;
    unsigned long long* fsum    = (unsigned long long*)ws;        // 8 B
    unsigned int*       counter = (unsigned int*)(ws + 8);        // 4 B
    float*              logacc  = (float*)(ws + 64);              // 16 KB

    k_hist<<<1, 1024, 0, stream>>>(tg, B, logacc, fsum, counter);
    k_row <<<B, 256, 0, stream>>>(outp, tg, logacc, fsum, counter, out, B);
}